// Round 1
// baseline (8955.055 us; speedup 1.0000x reference)
//
#include <hip/hip_runtime.h>

// ---------------- types / helpers ----------------
typedef __attribute__((ext_vector_type(8))) short bf16x8;
typedef __attribute__((ext_vector_type(4))) float floatx4;

__device__ __forceinline__ short f2bf(float f) {
  unsigned u = __float_as_uint(f);
  unsigned r = (u + 0x7fffu + ((u >> 16) & 1u)) >> 16;  // RNE
  return (short)r;
}
__device__ __forceinline__ float bf2f(short s) {
  return __uint_as_float(((unsigned)(unsigned short)s) << 16);
}

// ---- transpose + convert: W [K][N] f32 -> Wt [N][K] bf16 ----
__global__ __launch_bounds__(256) void transpose_convert(
    const float* __restrict__ W, short* __restrict__ Wt, int K, int N) {
  __shared__ float tile[32][33];
  const int nt = N >> 5;
  const int bx = blockIdx.x % nt;  // n tile
  const int by = blockIdx.x / nt;  // k tile
  const int tx = threadIdx.x & 31, ty = threadIdx.x >> 5;
#pragma unroll
  for (int i = 0; i < 32; i += 8)
    tile[ty + i][tx] = W[(size_t)(by * 32 + ty + i) * N + bx * 32 + tx];
  __syncthreads();
#pragma unroll
  for (int i = 0; i < 32; i += 8)
    Wt[(size_t)(bx * 32 + ty + i) * K + by * 32 + tx] = f2bf(tile[tx][ty + i]);
}

// ---- convert h0 f32[65536] -> bf16 row 0 of hsb ----
__global__ __launch_bounds__(256) void convert_h0(
    const float* __restrict__ h0, short* __restrict__ dst) {
  const int base = (blockIdx.x * 256 + threadIdx.x) * 4;
#pragma unroll
  for (int j = 0; j < 4; ++j) dst[base + j] = f2bf(h0[base + j]);
}

// ---- generic bf16 MFMA GEMM: C[M][N] = A[M][K] * Bt[N][K]^T + bias ----
// A_F32: A is f32 (convert while staging); else A is bf16.
// OUT_BF16: write bf16, else f32.
template <int A_F32, int OUT_BF16>
__global__ __launch_bounds__(256) void gemm_kernel(
    const void* __restrict__ Aptr, const short* __restrict__ Bt,
    const float* __restrict__ bias, void* __restrict__ Cptr,
    int M, int N, int K) {
  __shared__ short As[128 * 32];
  __shared__ short Bs[128 * 32];
  const int tid = threadIdx.x;
  const int lane = tid & 63;
  const int wv = tid >> 6;
  const int wr = wv >> 1, wc = wv & 1;
  const int nb = N >> 7;
  const int m0 = (blockIdx.x / nb) * 128;
  const int n0 = (blockIdx.x % nb) * 128;
  const int m = lane & 15, q = lane >> 4;
  const int sr = tid >> 1;            // staging row 0..127
  const int sh = (tid & 1) * 16;      // staging k-half 0/16

  floatx4 acc[4][4];
#pragma unroll
  for (int i = 0; i < 4; ++i)
#pragma unroll
    for (int j = 0; j < 4; ++j) acc[i][j] = (floatx4){0.f, 0.f, 0.f, 0.f};

  for (int kt = 0; kt < K; kt += 32) {
    // ---- stage A tile (128 x 32) ----
    if (A_F32) {
      const float* A = (const float*)Aptr;
      const float* src = A + (size_t)(m0 + sr) * K + kt + sh;
      const float4 f0 = ((const float4*)src)[0];
      const float4 f1 = ((const float4*)src)[1];
      const float4 f2 = ((const float4*)src)[2];
      const float4 f3 = ((const float4*)src)[3];
      bf16x8 p0, p1;
      p0[0] = f2bf(f0.x); p0[1] = f2bf(f0.y); p0[2] = f2bf(f0.z); p0[3] = f2bf(f0.w);
      p0[4] = f2bf(f1.x); p0[5] = f2bf(f1.y); p0[6] = f2bf(f1.z); p0[7] = f2bf(f1.w);
      p1[0] = f2bf(f2.x); p1[1] = f2bf(f2.y); p1[2] = f2bf(f2.z); p1[3] = f2bf(f2.w);
      p1[4] = f2bf(f3.x); p1[5] = f2bf(f3.y); p1[6] = f2bf(f3.z); p1[7] = f2bf(f3.w);
      *(bf16x8*)&As[sr * 32 + sh] = p0;
      *(bf16x8*)&As[sr * 32 + sh + 8] = p1;
    } else {
      const short* A = (const short*)Aptr;
      const short* src = A + (size_t)(m0 + sr) * K + kt + sh;
      *(bf16x8*)&As[sr * 32 + sh] = *(const bf16x8*)src;
      *(bf16x8*)&As[sr * 32 + sh + 8] = *(const bf16x8*)(src + 8);
    }
    // ---- stage B tile (128 n-rows x 32 k) from Bt[N][K] ----
    {
      const short* src = Bt + (size_t)(n0 + sr) * K + kt + sh;
      *(bf16x8*)&Bs[sr * 32 + sh] = *(const bf16x8*)src;
      *(bf16x8*)&Bs[sr * 32 + sh + 8] = *(const bf16x8*)(src + 8);
    }
    __syncthreads();
    bf16x8 af[4], bfr[4];
#pragma unroll
    for (int i = 0; i < 4; ++i)
      af[i] = *(bf16x8*)&As[(wr * 64 + i * 16 + m) * 32 + q * 8];
#pragma unroll
    for (int j = 0; j < 4; ++j)
      bfr[j] = *(bf16x8*)&Bs[(wc * 64 + j * 16 + m) * 32 + q * 8];
#pragma unroll
    for (int i = 0; i < 4; ++i)
#pragma unroll
      for (int j = 0; j < 4; ++j)
        acc[i][j] = __builtin_amdgcn_mfma_f32_16x16x32_bf16(af[i], bfr[j], acc[i][j], 0, 0, 0);
    __syncthreads();
  }
  // ---- epilogue: D col = lane&15, row = q*4 + reg ----
#pragma unroll
  for (int i = 0; i < 4; ++i) {
#pragma unroll
    for (int j = 0; j < 4; ++j) {
      const int row0 = m0 + wr * 64 + i * 16 + q * 4;
      const int col = n0 + wc * 64 + j * 16 + m;
      const float bv = bias[col];
#pragma unroll
      for (int r2 = 0; r2 < 4; ++r2) {
        const float v = acc[i][j][r2] + bv;
        if (OUT_BF16)
          ((short*)Cptr)[(size_t)(row0 + r2) * N + col] = f2bf(v);
        else
          ((float*)Cptr)[(size_t)(row0 + r2) * N + col] = v;
      }
    }
  }
}

// ---- persistent cooperative scan kernel ----
// grid 256 blocks x 256 thr. block = (batch-tile bt of 16) x (col-tile ct of 16).
// 4 waves split K=1024 into 256-chunks; W_hh slice held in registers for all 512 steps.
__global__ __launch_bounds__(256) void scan_kernel(
    const short* __restrict__ whh_t, const short* __restrict__ xh,
    short* __restrict__ hsb, float* __restrict__ hfinal,
    unsigned* __restrict__ cnt) {
  __shared__ float red[1024];
  const int tid = threadIdx.x;
  const int lane = tid & 63;
  const int w = tid >> 6;
  const int bt = blockIdx.x >> 6;
  const int ct = blockIdx.x & 63;
  const int m = lane & 15, q = lane >> 4;

  // W_hh fragments, resident in VGPRs for the whole scan.
  bf16x8 wf[8];
  {
    const int n = ct * 16 + m;
#pragma unroll
    for (int mf = 0; mf < 8; ++mf) {
      const int k = w * 256 + mf * 32 + q * 8;
      wf[mf] = *(const bf16x8*)&whh_t[(size_t)n * 1024 + k];
    }
  }
  const int arow = bt * 16 + m;
  const int rr = tid >> 4, cc = tid & 15;
  const int gm = bt * 16 + rr, gn = ct * 16 + cc;

  for (int t = 0; t < 512; ++t) {
    const short* hprev = hsb + (size_t)t * 65536;
    floatx4 acc = {0.f, 0.f, 0.f, 0.f};
#pragma unroll
    for (int mf = 0; mf < 8; ++mf) {
      const int k = w * 256 + mf * 32 + q * 8;
      const bf16x8 af = *(const bf16x8*)&hprev[(size_t)arow * 1024 + k];
      acc = __builtin_amdgcn_mfma_f32_16x16x32_bf16(af, wf[mf], acc, 0, 0, 0);
    }
    // partial 16x16 tiles -> LDS, reduce over 4 k-waves
#pragma unroll
    for (int r2 = 0; r2 < 4; ++r2)
      red[w * 256 + (q * 4 + r2) * 16 + m] = acc[r2];
    __syncthreads();
    float s = red[tid] + red[256 + tid] + red[512 + tid] + red[768 + tid];
    s += bf2f(xh[(size_t)t * 65536 + gm * 1024 + gn]);
    const float y = tanhf(s);
    hsb[(size_t)(t + 1) * 65536 + gm * 1024 + gn] = f2bf(y);
    if (t == 511) hfinal[gm * 1024 + gn] = y;
    __syncthreads();
    // grid barrier (monotonic counter, device-scope)
    if (tid == 0) {
      __threadfence();
      atomicAdd(cnt, 1u);
      const unsigned target = 256u * (unsigned)(t + 1);
      while (__hip_atomic_load(cnt, __ATOMIC_RELAXED, __HIP_MEMORY_SCOPE_AGENT) < target)
        __builtin_amdgcn_s_sleep(2);
      __threadfence();
    }
    __syncthreads();
  }
}

// ---------------- launcher ----------------
extern "C" void kernel_launch(void* const* d_in, const int* in_sizes, int n_in,
                              void* d_out, int out_size, void* d_ws, size_t ws_size,
                              hipStream_t stream) {
  (void)in_sizes; (void)n_in; (void)out_size; (void)ws_size;
  const float* inputs = (const float*)d_in[0];  // [512,64,512]
  const float* hidden = (const float*)d_in[1];  // [64,1024]
  const float* W_xh = (const float*)d_in[2];    // [512,1024]
  const float* W_hh = (const float*)d_in[3];    // [1024,1024]
  const float* b_h = (const float*)d_in[4];     // [1024]
  const float* W_hq = (const float*)d_in[5];    // [1024,512]
  const float* b_q = (const float*)d_in[6];     // [512]
  float* out = (float*)d_out;                   // 32768*512 outputs + 65536 hidden_final

  char* ws = (char*)d_ws;
  size_t o = 0;
  short* xh = (short*)(ws + o);    o += (size_t)512 * 64 * 1024 * 2;    // bf16 [512][64][1024]
  short* hsb = (short*)(ws + o);   o += (size_t)513 * 64 * 1024 * 2;    // bf16 [513][64][1024]
  short* wxh_t = (short*)(ws + o); o += (size_t)1024 * 512 * 2;         // bf16 [1024][512]
  short* whh_t = (short*)(ws + o); o += (size_t)1024 * 1024 * 2;        // bf16 [1024][1024]
  short* whq_t = (short*)(ws + o); o += (size_t)512 * 1024 * 2;         // bf16 [512][1024]
  unsigned* cnt = (unsigned*)(ws + o); o += 256;
  float* hfinal = out + (size_t)32768 * 512;

  hipMemsetAsync(cnt, 0, 8, stream);
  transpose_convert<<<dim3((512 / 32) * (1024 / 32)), dim3(256), 0, stream>>>(W_xh, wxh_t, 512, 1024);
  transpose_convert<<<dim3((1024 / 32) * (1024 / 32)), dim3(256), 0, stream>>>(W_hh, whh_t, 1024, 1024);
  transpose_convert<<<dim3((1024 / 32) * (512 / 32)), dim3(256), 0, stream>>>(W_hq, whq_t, 1024, 512);
  convert_h0<<<dim3(64), dim3(256), 0, stream>>>(hidden, hsb);

  // GEMM1: xh(bf16) = inputs(f32) @ W_xh + b_h   M=32768 N=1024 K=512
  gemm_kernel<1, 1><<<dim3((32768 / 128) * (1024 / 128)), dim3(256), 0, stream>>>(
      (const void*)inputs, wxh_t, b_h, (void*)xh, 32768, 1024, 512);

  // scan (cooperative)
  {
    void* kargs[5];
    kargs[0] = (void*)&whh_t;
    kargs[1] = (void*)&xh;
    kargs[2] = (void*)&hsb;
    kargs[3] = (void*)&hfinal;
    kargs[4] = (void*)&cnt;
    hipLaunchCooperativeKernel((const void*)scan_kernel, dim3(256), dim3(256), kargs, 0, stream);
  }

  // GEMM3: out(f32) = hs(bf16) @ W_hq + b_q   M=32768 N=512 K=1024
  gemm_kernel<0, 0><<<dim3((32768 / 128) * (512 / 128)), dim3(256), 0, stream>>>(
      (const void*)(hsb + 65536), whq_t, b_q, (void*)out, 32768, 512, 1024);
}

// Round 2
// 6830.002 us; speedup vs baseline: 1.3111x; 1.3111x over previous
//
#include <hip/hip_runtime.h>

// ---------------- types / helpers ----------------
typedef __attribute__((ext_vector_type(8))) short bf16x8;
typedef __attribute__((ext_vector_type(4))) float floatx4;

__device__ __forceinline__ short f2bf(float f) {
  unsigned u = __float_as_uint(f);
  unsigned r = (u + 0x7fffu + ((u >> 16) & 1u)) >> 16;  // RNE
  return (short)r;
}
__device__ __forceinline__ float bf2f(short s) {
  return __uint_as_float(((unsigned)(unsigned short)s) << 16);
}

// ---- transpose + convert: W [K][N] f32 -> Wt [N][K] bf16 ----
__global__ __launch_bounds__(256) void transpose_convert(
    const float* __restrict__ W, short* __restrict__ Wt, int K, int N) {
  __shared__ float tile[32][33];
  const int nt = N >> 5;
  const int bx = blockIdx.x % nt;  // n tile
  const int by = blockIdx.x / nt;  // k tile
  const int tx = threadIdx.x & 31, ty = threadIdx.x >> 5;
#pragma unroll
  for (int i = 0; i < 32; i += 8)
    tile[ty + i][tx] = W[(size_t)(by * 32 + ty + i) * N + bx * 32 + tx];
  __syncthreads();
#pragma unroll
  for (int i = 0; i < 32; i += 8)
    Wt[(size_t)(bx * 32 + ty + i) * K + by * 32 + tx] = f2bf(tile[tx][ty + i]);
}

// ---- convert h0 f32[65536] -> bf16 row 0 of hsb ----
__global__ __launch_bounds__(256) void convert_h0(
    const float* __restrict__ h0, short* __restrict__ dst) {
  const int base = (blockIdx.x * 256 + threadIdx.x) * 4;
#pragma unroll
  for (int j = 0; j < 4; ++j) dst[base + j] = f2bf(h0[base + j]);
}

// ---- generic bf16 MFMA GEMM: C[M][N] = A[M][K] * Bt[N][K]^T + bias ----
template <int A_F32, int OUT_BF16>
__global__ __launch_bounds__(256) void gemm_kernel(
    const void* __restrict__ Aptr, const short* __restrict__ Bt,
    const float* __restrict__ bias, void* __restrict__ Cptr,
    int M, int N, int K) {
  __shared__ short As[128 * 32];
  __shared__ short Bs[128 * 32];
  const int tid = threadIdx.x;
  const int lane = tid & 63;
  const int wv = tid >> 6;
  const int wr = wv >> 1, wc = wv & 1;
  const int nb = N >> 7;
  const int m0 = (blockIdx.x / nb) * 128;
  const int n0 = (blockIdx.x % nb) * 128;
  const int m = lane & 15, q = lane >> 4;
  const int sr = tid >> 1;
  const int sh = (tid & 1) * 16;

  floatx4 acc[4][4];
#pragma unroll
  for (int i = 0; i < 4; ++i)
#pragma unroll
    for (int j = 0; j < 4; ++j) acc[i][j] = (floatx4){0.f, 0.f, 0.f, 0.f};

  for (int kt = 0; kt < K; kt += 32) {
    if (A_F32) {
      const float* A = (const float*)Aptr;
      const float* src = A + (size_t)(m0 + sr) * K + kt + sh;
      const float4 f0 = ((const float4*)src)[0];
      const float4 f1 = ((const float4*)src)[1];
      const float4 f2 = ((const float4*)src)[2];
      const float4 f3 = ((const float4*)src)[3];
      bf16x8 p0, p1;
      p0[0] = f2bf(f0.x); p0[1] = f2bf(f0.y); p0[2] = f2bf(f0.z); p0[3] = f2bf(f0.w);
      p0[4] = f2bf(f1.x); p0[5] = f2bf(f1.y); p0[6] = f2bf(f1.z); p0[7] = f2bf(f1.w);
      p1[0] = f2bf(f2.x); p1[1] = f2bf(f2.y); p1[2] = f2bf(f2.z); p1[3] = f2bf(f2.w);
      p1[4] = f2bf(f3.x); p1[5] = f2bf(f3.y); p1[6] = f2bf(f3.z); p1[7] = f2bf(f3.w);
      *(bf16x8*)&As[sr * 32 + sh] = p0;
      *(bf16x8*)&As[sr * 32 + sh + 8] = p1;
    } else {
      const short* A = (const short*)Aptr;
      const short* src = A + (size_t)(m0 + sr) * K + kt + sh;
      *(bf16x8*)&As[sr * 32 + sh] = *(const bf16x8*)src;
      *(bf16x8*)&As[sr * 32 + sh + 8] = *(const bf16x8*)(src + 8);
    }
    {
      const short* src = Bt + (size_t)(n0 + sr) * K + kt + sh;
      *(bf16x8*)&Bs[sr * 32 + sh] = *(const bf16x8*)src;
      *(bf16x8*)&Bs[sr * 32 + sh + 8] = *(const bf16x8*)(src + 8);
    }
    __syncthreads();
    bf16x8 af[4], bfr[4];
#pragma unroll
    for (int i = 0; i < 4; ++i)
      af[i] = *(bf16x8*)&As[(wr * 64 + i * 16 + m) * 32 + q * 8];
#pragma unroll
    for (int j = 0; j < 4; ++j)
      bfr[j] = *(bf16x8*)&Bs[(wc * 64 + j * 16 + m) * 32 + q * 8];
#pragma unroll
    for (int i = 0; i < 4; ++i)
#pragma unroll
      for (int j = 0; j < 4; ++j)
        acc[i][j] = __builtin_amdgcn_mfma_f32_16x16x32_bf16(af[i], bfr[j], acc[i][j], 0, 0, 0);
    __syncthreads();
  }
#pragma unroll
  for (int i = 0; i < 4; ++i) {
#pragma unroll
    for (int j = 0; j < 4; ++j) {
      const int row0 = m0 + wr * 64 + i * 16 + q * 4;
      const int col = n0 + wc * 64 + j * 16 + m;
      const float bv = bias[col];
#pragma unroll
      for (int r2 = 0; r2 < 4; ++r2) {
        const float v = acc[i][j][r2] + bv;
        if (OUT_BF16)
          ((short*)Cptr)[(size_t)(row0 + r2) * N + col] = f2bf(v);
        else
          ((float*)Cptr)[(size_t)(row0 + r2) * N + col] = v;
      }
    }
  }
}

// ---- persistent cooperative scan kernel ----
// 64 blocks x 1024 threads. block = (bt in [0,4): 16 batch rows) x (nt in [0,16): 64 cols).
// 16 waves = 4 n-subtiles x 4 k-chunks; W_hh slice (16n x 256K per wave) in VGPRs.
// Grid barrier: per-block monotonic flag on its own cacheline; wave0 of every
// block polls all 64 flags with 64 lanes in parallel (no atomic contention).
__global__ __launch_bounds__(1024) void scan_kernel(
    const short* __restrict__ whh_t, const short* __restrict__ xh,
    short* __restrict__ hsb, float* __restrict__ hfinal,
    unsigned* __restrict__ flags) {
  __shared__ float red[16 * 256];
  const int tid = threadIdx.x;
  const int lane = tid & 63;
  const int w = tid >> 6;
  const int ns = w >> 2;       // n-subtile 0..3 (16 cols)
  const int kg = w & 3;        // k-chunk 0..3 (256 K)
  const int bt = blockIdx.x >> 4;   // 16 batch rows
  const int nt = blockIdx.x & 15;   // 64 cols
  const int m = lane & 15, q = lane >> 4;

  // W_hh fragments resident in VGPRs for all 512 steps.
  bf16x8 wf[8];
  {
    const int n = nt * 64 + ns * 16 + m;
#pragma unroll
    for (int ks = 0; ks < 8; ++ks)
      wf[ks] = *(const bf16x8*)&whh_t[(size_t)n * 1024 + kg * 256 + ks * 32 + q * 8];
  }
  const int arow = bt * 16 + m;
  // epilogue indices
  const int ns2 = tid >> 8;
  const int idx = tid & 255;
  const int gm = bt * 16 + (idx >> 4);
  const int gn = nt * 64 + ns2 * 16 + (idx & 15);

  unsigned* myflag = flags + blockIdx.x * 32;  // 128B stride

  for (int t = 0; t < 512; ++t) {
    const short* hprev = hsb + (size_t)t * 65536;
    floatx4 acc = {0.f, 0.f, 0.f, 0.f};
#pragma unroll
    for (int ks = 0; ks < 8; ++ks) {
      const bf16x8 af =
          *(const bf16x8*)&hprev[(size_t)arow * 1024 + kg * 256 + ks * 32 + q * 8];
      acc = __builtin_amdgcn_mfma_f32_16x16x32_bf16(af, wf[ks], acc, 0, 0, 0);
    }
#pragma unroll
    for (int r2 = 0; r2 < 4; ++r2)
      red[w * 256 + (q * 4 + r2) * 16 + m] = acc[r2];
    __syncthreads();
    float s = red[ns2 * 1024 + idx] + red[ns2 * 1024 + 256 + idx] +
              red[ns2 * 1024 + 512 + idx] + red[ns2 * 1024 + 768 + idx];
    s += bf2f(xh[(size_t)t * 65536 + gm * 1024 + gn]);
    const float y = tanhf(s);
    hsb[(size_t)(t + 1) * 65536 + gm * 1024 + gn] = f2bf(y);
    if (t == 511) hfinal[gm * 1024 + gn] = y;
    __syncthreads();  // drains vmcnt: all h' stores are at least in L2
    if (tid == 0) {
      __builtin_amdgcn_fence(__ATOMIC_RELEASE, "agent");  // wbl2: flush to LLC
      __hip_atomic_store(myflag, (unsigned)(t + 1), __ATOMIC_RELAXED,
                         __HIP_MEMORY_SCOPE_AGENT);
    }
    if (tid < 64) {
      const unsigned* fp = flags + lane * 32;
      while (true) {
        unsigned v = __hip_atomic_load(fp, __ATOMIC_RELAXED, __HIP_MEMORY_SCOPE_AGENT);
        if (__all((int)(v > (unsigned)t))) break;
        __builtin_amdgcn_s_sleep(1);
      }
    }
    __syncthreads();
    __builtin_amdgcn_fence(__ATOMIC_ACQUIRE, "agent");  // inv L1/L2: see peers' h'
  }
}

// ---------------- launcher ----------------
extern "C" void kernel_launch(void* const* d_in, const int* in_sizes, int n_in,
                              void* d_out, int out_size, void* d_ws, size_t ws_size,
                              hipStream_t stream) {
  (void)in_sizes; (void)n_in; (void)out_size; (void)ws_size;
  const float* inputs = (const float*)d_in[0];  // [512,64,512]
  const float* hidden = (const float*)d_in[1];  // [64,1024]
  const float* W_xh = (const float*)d_in[2];    // [512,1024]
  const float* W_hh = (const float*)d_in[3];    // [1024,1024]
  const float* b_h = (const float*)d_in[4];     // [1024]
  const float* W_hq = (const float*)d_in[5];    // [1024,512]
  const float* b_q = (const float*)d_in[6];     // [512]
  float* out = (float*)d_out;

  char* ws = (char*)d_ws;
  size_t o = 0;
  short* xh = (short*)(ws + o);    o += (size_t)512 * 64 * 1024 * 2;
  short* hsb = (short*)(ws + o);   o += (size_t)513 * 64 * 1024 * 2;
  short* wxh_t = (short*)(ws + o); o += (size_t)1024 * 512 * 2;
  short* whh_t = (short*)(ws + o); o += (size_t)1024 * 1024 * 2;
  short* whq_t = (short*)(ws + o); o += (size_t)512 * 1024 * 2;
  unsigned* flags = (unsigned*)(ws + o); o += 64 * 32 * 4;
  float* hfinal = out + (size_t)32768 * 512;

  hipMemsetAsync(flags, 0, 64 * 32 * 4, stream);
  transpose_convert<<<dim3((512 / 32) * (1024 / 32)), dim3(256), 0, stream>>>(W_xh, wxh_t, 512, 1024);
  transpose_convert<<<dim3((1024 / 32) * (1024 / 32)), dim3(256), 0, stream>>>(W_hh, whh_t, 1024, 1024);
  transpose_convert<<<dim3((1024 / 32) * (512 / 32)), dim3(256), 0, stream>>>(W_hq, whq_t, 1024, 512);
  convert_h0<<<dim3(64), dim3(256), 0, stream>>>(hidden, hsb);

  gemm_kernel<1, 1><<<dim3((32768 / 128) * (1024 / 128)), dim3(256), 0, stream>>>(
      (const void*)inputs, wxh_t, b_h, (void*)xh, 32768, 1024, 512);

  {
    static void* kargs[5];
    kargs[0] = (void*)&whh_t;
    kargs[1] = (void*)&xh;
    kargs[2] = (void*)&hsb;
    kargs[3] = (void*)&hfinal;
    kargs[4] = (void*)&flags;
    hipLaunchCooperativeKernel((const void*)scan_kernel, dim3(64), dim3(1024), kargs, 0, stream);
  }

  gemm_kernel<0, 0><<<dim3((32768 / 128) * (512 / 128)), dim3(256), 0, stream>>>(
      (const void*)(hsb + 65536), whq_t, b_q, (void*)out, 32768, 512, 1024);
}

// Round 3
// 1953.009 us; speedup vs baseline: 4.5853x; 3.4972x over previous
//
#include <hip/hip_runtime.h>

// ---------------- types / helpers ----------------
typedef __attribute__((ext_vector_type(8))) short bf16x8;
typedef __attribute__((ext_vector_type(4))) float floatx4;
typedef unsigned long long u64;

__device__ __forceinline__ short f2bf(float f) {
  unsigned u = __float_as_uint(f);
  unsigned r = (u + 0x7fffu + ((u >> 16) & 1u)) >> 16;  // RNE
  return (short)r;
}
__device__ __forceinline__ float bf2f(short s) {
  return __uint_as_float(((unsigned)(unsigned short)s) << 16);
}

// ---- transpose + convert: W [K][N] f32 -> Wt [N][K] bf16 ----
__global__ __launch_bounds__(256) void transpose_convert(
    const float* __restrict__ W, short* __restrict__ Wt, int K, int N) {
  __shared__ float tile[32][33];
  const int nt = N >> 5;
  const int bx = blockIdx.x % nt;  // n tile
  const int by = blockIdx.x / nt;  // k tile
  const int tx = threadIdx.x & 31, ty = threadIdx.x >> 5;
#pragma unroll
  for (int i = 0; i < 32; i += 8)
    tile[ty + i][tx] = W[(size_t)(by * 32 + ty + i) * N + bx * 32 + tx];
  __syncthreads();
#pragma unroll
  for (int i = 0; i < 32; i += 8)
    Wt[(size_t)(bx * 32 + ty + i) * K + by * 32 + tx] = f2bf(tile[tx][ty + i]);
}

// ---- convert h0 f32[65536] -> bf16 row 0 of hsb ----
__global__ __launch_bounds__(256) void convert_h0(
    const float* __restrict__ h0, short* __restrict__ dst) {
  const int base = (blockIdx.x * 256 + threadIdx.x) * 4;
#pragma unroll
  for (int j = 0; j < 4; ++j) dst[base + j] = f2bf(h0[base + j]);
}

// ---- generic bf16 MFMA GEMM: C[M][N] = A[M][K] * Bt[N][K]^T + bias ----
template <int A_F32, int OUT_BF16>
__global__ __launch_bounds__(256) void gemm_kernel(
    const void* __restrict__ Aptr, const short* __restrict__ Bt,
    const float* __restrict__ bias, void* __restrict__ Cptr,
    int M, int N, int K) {
  __shared__ short As[128 * 32];
  __shared__ short Bs[128 * 32];
  const int tid = threadIdx.x;
  const int lane = tid & 63;
  const int wv = tid >> 6;
  const int wr = wv >> 1, wc = wv & 1;
  const int nb = N >> 7;
  const int m0 = (blockIdx.x / nb) * 128;
  const int n0 = (blockIdx.x % nb) * 128;
  const int m = lane & 15, q = lane >> 4;
  const int sr = tid >> 1;
  const int sh = (tid & 1) * 16;

  floatx4 acc[4][4];
#pragma unroll
  for (int i = 0; i < 4; ++i)
#pragma unroll
    for (int j = 0; j < 4; ++j) acc[i][j] = (floatx4){0.f, 0.f, 0.f, 0.f};

  for (int kt = 0; kt < K; kt += 32) {
    if (A_F32) {
      const float* A = (const float*)Aptr;
      const float* src = A + (size_t)(m0 + sr) * K + kt + sh;
      const float4 f0 = ((const float4*)src)[0];
      const float4 f1 = ((const float4*)src)[1];
      const float4 f2 = ((const float4*)src)[2];
      const float4 f3 = ((const float4*)src)[3];
      bf16x8 p0, p1;
      p0[0] = f2bf(f0.x); p0[1] = f2bf(f0.y); p0[2] = f2bf(f0.z); p0[3] = f2bf(f0.w);
      p0[4] = f2bf(f1.x); p0[5] = f2bf(f1.y); p0[6] = f2bf(f1.z); p0[7] = f2bf(f1.w);
      p1[0] = f2bf(f2.x); p1[1] = f2bf(f2.y); p1[2] = f2bf(f2.z); p1[3] = f2bf(f2.w);
      p1[4] = f2bf(f3.x); p1[5] = f2bf(f3.y); p1[6] = f2bf(f3.z); p1[7] = f2bf(f3.w);
      *(bf16x8*)&As[sr * 32 + sh] = p0;
      *(bf16x8*)&As[sr * 32 + sh + 8] = p1;
    } else {
      const short* A = (const short*)Aptr;
      const short* src = A + (size_t)(m0 + sr) * K + kt + sh;
      *(bf16x8*)&As[sr * 32 + sh] = *(const bf16x8*)src;
      *(bf16x8*)&As[sr * 32 + sh + 8] = *(const bf16x8*)(src + 8);
    }
    {
      const short* src = Bt + (size_t)(n0 + sr) * K + kt + sh;
      *(bf16x8*)&Bs[sr * 32 + sh] = *(const bf16x8*)src;
      *(bf16x8*)&Bs[sr * 32 + sh + 8] = *(const bf16x8*)(src + 8);
    }
    __syncthreads();
    bf16x8 af[4], bfr[4];
#pragma unroll
    for (int i = 0; i < 4; ++i)
      af[i] = *(bf16x8*)&As[(wr * 64 + i * 16 + m) * 32 + q * 8];
#pragma unroll
    for (int j = 0; j < 4; ++j)
      bfr[j] = *(bf16x8*)&Bs[(wc * 64 + j * 16 + m) * 32 + q * 8];
#pragma unroll
    for (int i = 0; i < 4; ++i)
#pragma unroll
      for (int j = 0; j < 4; ++j)
        acc[i][j] = __builtin_amdgcn_mfma_f32_16x16x32_bf16(af[i], bfr[j], acc[i][j], 0, 0, 0);
    __syncthreads();
  }
#pragma unroll
  for (int i = 0; i < 4; ++i) {
#pragma unroll
    for (int j = 0; j < 4; ++j) {
      const int row0 = m0 + wr * 64 + i * 16 + q * 4;
      const int col = n0 + wc * 64 + j * 16 + m;
      const float bv = bias[col];
#pragma unroll
      for (int r2 = 0; r2 < 4; ++r2) {
        const float v = acc[i][j][r2] + bv;
        if (OUT_BF16)
          ((short*)Cptr)[(size_t)(row0 + r2) * N + col] = f2bf(v);
        else
          ((float*)Cptr)[(size_t)(row0 + r2) * N + col] = v;
      }
    }
  }
}

// ---- persistent cooperative scan kernel ----
// 64 blocks x 1024 threads. block = (bt: 16 batch rows) x (nt: 64 cols).
// All cross-block data moves via agent-scope atomics (L2-bypass, LLC-coherent)
// -> NO agent fences (no buffer_wbl2 / buffer_inv per step).
__global__ __launch_bounds__(1024) void scan_kernel(
    const short* __restrict__ whh_t, const short* __restrict__ xh,
    short* __restrict__ hsb, float* __restrict__ hfinal,
    unsigned* __restrict__ flags) {
  __shared__ float red[16 * 256];
  __shared__ short hin[16 * 1032];  // 16 rows x 1024 K, stride 1032 (2-way-free banks)
  __shared__ short hout[1024];      // 16 rows x 64 cols
  const int tid = threadIdx.x;
  const int lane = tid & 63;
  const int w = tid >> 6;
  const int ns = w >> 2;  // n-subtile 0..3
  const int kg = w & 3;   // k-chunk 0..3
  const int bt = blockIdx.x >> 4;
  const int nt = blockIdx.x & 15;
  const int m = lane & 15, q = lane >> 4;

  // W_hh fragments resident in VGPRs for all 512 steps.
  bf16x8 wf[8];
  {
    const int n = nt * 64 + ns * 16 + m;
#pragma unroll
    for (int ks = 0; ks < 8; ++ks)
      wf[ks] = *(const bf16x8*)&whh_t[(size_t)n * 1024 + kg * 256 + ks * 32 + q * 8];
  }
  // epilogue indices
  const int ns2 = tid >> 8;
  const int idx = tid & 255;
  const int lr = idx >> 4;
  const int lc = ns2 * 16 + (idx & 15);
  const int gm = bt * 16 + lr, gn = nt * 64 + lc;
  // staging indices: 32 B (16 elems) per thread, rows of 1024
  const int se = tid * 16;
  const int srow = se >> 10, scol = se & 1023;

  unsigned* myflag = flags + blockIdx.x * 32;  // 128B stride

  for (int t = 0; t < 512; ++t) {
    // prefetch xh element (normal cached load; hide HBM latency behind staging+MFMA)
    const short xv = xh[(size_t)t * 65536 + (size_t)gm * 1024 + gn];
    // ---- stage h(t) into LDS via L2-bypass loads ----
    {
      const u64* src = (const u64*)(hsb + (size_t)t * 65536 +
                                    (size_t)(bt * 16 + srow) * 1024 + scol);
      u64 a0 = __hip_atomic_load(src + 0, __ATOMIC_RELAXED, __HIP_MEMORY_SCOPE_AGENT);
      u64 a1 = __hip_atomic_load(src + 1, __ATOMIC_RELAXED, __HIP_MEMORY_SCOPE_AGENT);
      u64 a2 = __hip_atomic_load(src + 2, __ATOMIC_RELAXED, __HIP_MEMORY_SCOPE_AGENT);
      u64 a3 = __hip_atomic_load(src + 3, __ATOMIC_RELAXED, __HIP_MEMORY_SCOPE_AGENT);
      u64* d = (u64*)&hin[srow * 1032 + scol];
      d[0] = a0; d[1] = a1; d[2] = a2; d[3] = a3;
    }
    __syncthreads();
    floatx4 acc = {0.f, 0.f, 0.f, 0.f};
#pragma unroll
    for (int ks = 0; ks < 8; ++ks) {
      const bf16x8 af = *(const bf16x8*)&hin[m * 1032 + kg * 256 + ks * 32 + q * 8];
      acc = __builtin_amdgcn_mfma_f32_16x16x32_bf16(af, wf[ks], acc, 0, 0, 0);
    }
#pragma unroll
    for (int r2 = 0; r2 < 4; ++r2)
      red[w * 256 + (q * 4 + r2) * 16 + m] = acc[r2];
    __syncthreads();
    float s = red[ns2 * 1024 + idx] + red[ns2 * 1024 + 256 + idx] +
              red[ns2 * 1024 + 512 + idx] + red[ns2 * 1024 + 768 + idx];
    s += bf2f(xv);
    const float y = tanhf(s);
    hout[lr * 64 + lc] = f2bf(y);
    if (t == 511) hfinal[gm * 1024 + gn] = y;
    __syncthreads();
    // ---- publish h(t+1): coalesced 8B write-through stores (LLC-coherent) ----
    if (tid < 256) {
      const int e = tid * 4, r = e >> 6, c = e & 63;
      const u64 v = *(const u64*)&hout[e];
      u64* dst = (u64*)&hsb[(size_t)(t + 1) * 65536 +
                            (size_t)(bt * 16 + r) * 1024 + nt * 64 + c];
      __hip_atomic_store(dst, v, __ATOMIC_RELAXED, __HIP_MEMORY_SCOPE_AGENT);
    }
    __syncthreads();  // every wave drains vmcnt -> all h' stores acked at LLC
    if (tid == 0)
      __hip_atomic_store(myflag, (unsigned)(t + 1), __ATOMIC_RELAXED,
                         __HIP_MEMORY_SCOPE_AGENT);
    if (tid < 64) {
      const unsigned* fp = flags + lane * 32;
      while (true) {
        unsigned v = __hip_atomic_load(fp, __ATOMIC_RELAXED, __HIP_MEMORY_SCOPE_AGENT);
        if (__all((int)(v > (unsigned)t))) break;
        __builtin_amdgcn_s_sleep(1);
      }
    }
    __syncthreads();
  }
}

// ---------------- launcher ----------------
extern "C" void kernel_launch(void* const* d_in, const int* in_sizes, int n_in,
                              void* d_out, int out_size, void* d_ws, size_t ws_size,
                              hipStream_t stream) {
  (void)in_sizes; (void)n_in; (void)out_size; (void)ws_size;
  const float* inputs = (const float*)d_in[0];  // [512,64,512]
  const float* hidden = (const float*)d_in[1];  // [64,1024]
  const float* W_xh = (const float*)d_in[2];    // [512,1024]
  const float* W_hh = (const float*)d_in[3];    // [1024,1024]
  const float* b_h = (const float*)d_in[4];     // [1024]
  const float* W_hq = (const float*)d_in[5];    // [1024,512]
  const float* b_q = (const float*)d_in[6];     // [512]
  float* out = (float*)d_out;

  char* ws = (char*)d_ws;
  size_t o = 0;
  short* xh = (short*)(ws + o);    o += (size_t)512 * 64 * 1024 * 2;
  short* hsb = (short*)(ws + o);   o += (size_t)513 * 64 * 1024 * 2;
  short* wxh_t = (short*)(ws + o); o += (size_t)1024 * 512 * 2;
  short* whh_t = (short*)(ws + o); o += (size_t)1024 * 1024 * 2;
  short* whq_t = (short*)(ws + o); o += (size_t)512 * 1024 * 2;
  unsigned* flags = (unsigned*)(ws + o); o += 64 * 32 * 4;
  float* hfinal = out + (size_t)32768 * 512;

  hipMemsetAsync(flags, 0, 64 * 32 * 4, stream);
  transpose_convert<<<dim3((512 / 32) * (1024 / 32)), dim3(256), 0, stream>>>(W_xh, wxh_t, 512, 1024);
  transpose_convert<<<dim3((1024 / 32) * (1024 / 32)), dim3(256), 0, stream>>>(W_hh, whh_t, 1024, 1024);
  transpose_convert<<<dim3((1024 / 32) * (512 / 32)), dim3(256), 0, stream>>>(W_hq, whq_t, 1024, 512);
  convert_h0<<<dim3(64), dim3(256), 0, stream>>>(hidden, hsb);

  gemm_kernel<1, 1><<<dim3((32768 / 128) * (1024 / 128)), dim3(256), 0, stream>>>(
      (const void*)inputs, wxh_t, b_h, (void*)xh, 32768, 1024, 512);

  {
    void* kargs[5];
    kargs[0] = (void*)&whh_t;
    kargs[1] = (void*)&xh;
    kargs[2] = (void*)&hsb;
    kargs[3] = (void*)&hfinal;
    kargs[4] = (void*)&flags;
    hipLaunchCooperativeKernel((const void*)scan_kernel, dim3(64), dim3(1024), kargs, 0, stream);
  }

  gemm_kernel<0, 0><<<dim3((32768 / 128) * (512 / 128)), dim3(256), 0, stream>>>(
      (const void*)(hsb + 65536), whq_t, b_q, (void*)out, 32768, 512, 1024);
}